// Round 1
// baseline (630.508 us; speedup 1.0000x reference)
//
#include <hip/hip_runtime.h>
#include <hip/hip_bf16.h>
#include <math.h>

// GAT 2-layer fused pipeline for MI355X.
// Dims hard-coded per reference: D_IN=D_H=128, D_OUT=64, SLOPE=0.2.
// N and E derived from in_sizes. All math fp32.
//
// ws layout (floats / ints):
//   m_buf [N*128]  : m1, later m2
//   q_buf [N*128]  : q1, later q2 (N*64 used)
//   p_buf [N*128]  : p1, later p2
//   offs  [N+1], cursor [N], csr_src [E], bsum [ceil(N/256)]
// total ~80.5 MB for N=50000, E=800000.

#define SLOPE 0.2f

__device__ __forceinline__ float gelu_erf(float x) {
    return 0.5f * x * (1.0f + erff(x * 0.70710678118654752f));
}

// ---------------- GEMM: out[N,C] = act(A[N,128] @ W[128,C] + bias) ----------
// 256 threads. Each thread: 2 rows x 4 cols. A tile in LDS (padded rows),
// W streamed from global (64KB, L1/L2 resident).
template <int C, int ACT>
__global__ __launch_bounds__(256) void gemm_k128(
    const float* __restrict__ A, const float* __restrict__ W,
    const float* __restrict__ bias, float* __restrict__ out, int N)
{
    constexpr int CG   = C / 4;        // col groups of 4
    constexpr int TR   = 256 / CG;     // thread-rows
    constexpr int ROWS = TR * 2;       // rows per block (16 or 32)
    __shared__ float Alds[ROWS][132];  // +4 pad: distinct rows -> distinct banks

    const int row0 = blockIdx.x * ROWS;
    const int t = threadIdx.x;

    // stage A tile: ROWS*128 floats as float4, coalesced (32 float4 per row)
    constexpr int LD4 = (ROWS * 32) / 256;
#pragma unroll
    for (int i = 0; i < LD4; i++) {
        int idx = t + i * 256;
        int r = idx >> 5;
        int kc = idx & 31;
        float4 v = make_float4(0.f, 0.f, 0.f, 0.f);
        int gr = row0 + r;
        if (gr < N) v = reinterpret_cast<const float4*>(A + (size_t)gr * 128)[kc];
        reinterpret_cast<float4*>(&Alds[r][0])[kc] = v;  // 132*4=528B rows, 16B aligned
    }
    __syncthreads();

    const int cg = t % CG;
    const int rs = t / CG;
    const int r0 = rs * 2, r1 = r0 + 1;

    float4 acc0 = make_float4(0.f, 0.f, 0.f, 0.f);
    float4 acc1 = acc0;
    const float4* Wv = reinterpret_cast<const float4*>(W);

#pragma unroll 8
    for (int k = 0; k < 128; k++) {
        float4 w = Wv[k * CG + cg];
        float a0 = Alds[r0][k];
        float a1 = Alds[r1][k];
        acc0.x = fmaf(a0, w.x, acc0.x);
        acc0.y = fmaf(a0, w.y, acc0.y);
        acc0.z = fmaf(a0, w.z, acc0.z);
        acc0.w = fmaf(a0, w.w, acc0.w);
        acc1.x = fmaf(a1, w.x, acc1.x);
        acc1.y = fmaf(a1, w.y, acc1.y);
        acc1.z = fmaf(a1, w.z, acc1.z);
        acc1.w = fmaf(a1, w.w, acc1.w);
    }

    float4 b = reinterpret_cast<const float4*>(bias)[cg];
    acc0.x += b.x; acc0.y += b.y; acc0.z += b.z; acc0.w += b.w;
    acc1.x += b.x; acc1.y += b.y; acc1.z += b.z; acc1.w += b.w;
    if (ACT == 1) {
        acc0.x = gelu_erf(acc0.x); acc0.y = gelu_erf(acc0.y);
        acc0.z = gelu_erf(acc0.z); acc0.w = gelu_erf(acc0.w);
        acc1.x = gelu_erf(acc1.x); acc1.y = gelu_erf(acc1.y);
        acc1.z = gelu_erf(acc1.z); acc1.w = gelu_erf(acc1.w);
    }
    int gr0 = row0 + r0, gr1 = row0 + r1;
    if (gr0 < N) reinterpret_cast<float4*>(out + (size_t)gr0 * C)[cg] = acc0;
    if (gr1 < N) reinterpret_cast<float4*>(out + (size_t)gr1 * C)[cg] = acc1;
}

// ---------------- CSR build --------------------------------------------------
__global__ __launch_bounds__(256) void hist_kernel(const int* __restrict__ dst,
                                                   int* __restrict__ cnt, int E)
{
    int i = blockIdx.x * 256 + threadIdx.x;
    if (i < E) atomicAdd(&cnt[dst[i]], 1);
}

__global__ __launch_bounds__(256) void scan1_kernel(const int* __restrict__ cnt,
                                                    int* __restrict__ offs,
                                                    int* __restrict__ bsum, int N)
{
    __shared__ int lds[256];
    int t = threadIdx.x;
    int i = blockIdx.x * 256 + t;
    int v = (i < N) ? cnt[i] : 0;
    lds[t] = v;
    __syncthreads();
    int x = v;
    for (int off = 1; off < 256; off <<= 1) {
        int y = (t >= off) ? lds[t - off] : 0;
        __syncthreads();
        x += y;
        lds[t] = x;
        __syncthreads();
    }
    if (i < N) offs[i] = x - v;           // block-local exclusive
    if (t == 255) bsum[blockIdx.x] = x;   // block total
}

__global__ __launch_bounds__(256) void scan2_kernel(int* __restrict__ bsum, int NB)
{
    __shared__ int lds[256];
    int t = threadIdx.x;
    int v = (t < NB) ? bsum[t] : 0;
    lds[t] = v;
    __syncthreads();
    int x = v;
    for (int off = 1; off < 256; off <<= 1) {
        int y = (t >= off) ? lds[t - off] : 0;
        __syncthreads();
        x += y;
        lds[t] = x;
        __syncthreads();
    }
    if (t < NB) bsum[t] = x - v;          // exclusive block offsets
}

__global__ __launch_bounds__(256) void scan3_kernel(int* __restrict__ offs,
                                                    const int* __restrict__ bsum,
                                                    int* __restrict__ cursor,
                                                    int N, int E)
{
    int i = blockIdx.x * 256 + threadIdx.x;
    if (i < N) {
        int o = offs[i] + bsum[blockIdx.x];
        offs[i] = o;
        cursor[i] = o;
    }
    if (i == 0) offs[N] = E;
}

__global__ __launch_bounds__(256) void scatter_kernel(const int* __restrict__ src,
                                                      const int* __restrict__ dst,
                                                      int* __restrict__ cursor,
                                                      int* __restrict__ csr_src, int E)
{
    int i = blockIdx.x * 256 + threadIdx.x;
    if (i < E) {
        int d = dst[i];
        int pos = atomicAdd(&cursor[d], 1);
        csr_src[pos] = src[i];
    }
}

// ---------------- fused GAT edge-softmax + aggregation -----------------------
// One wave (64 lanes) per dst node. Lane holds D/64 dims.
// Single pass: acc = sum es*p[src], denom = sum es; out = epi(acc/denom).
// EPI 0: gelu(h + bvec) (layer1 -> m2);  EPI 1: h + bvec (layer2 -> out).
template <int D, int EPI>
__global__ __launch_bounds__(256) void gat_agg(
    const float* __restrict__ q, const float* __restrict__ p,
    const float* __restrict__ a, const float* __restrict__ bvec,
    const int* __restrict__ offs, const int* __restrict__ csr_src,
    float* __restrict__ out, int N)
{
    constexpr int VPL = D / 64;  // values per lane (2 or 1)
    int node = (int)((blockIdx.x * 256 + threadIdx.x) >> 6);
    int lane = threadIdx.x & 63;
    if (node >= N) return;  // wave-uniform exit (node is per-wave)

    float qv[VPL], av[VPL], acc[VPL];
#pragma unroll
    for (int v = 0; v < VPL; v++) {
        qv[v] = q[(size_t)node * D + lane * VPL + v];
        av[v] = a[lane * VPL + v];
        acc[v] = 0.f;
    }
    float denom = 0.f;

    int e0 = offs[node], e1 = offs[node + 1];
    for (int e = e0; e < e1; e++) {
        int s = csr_src[e];
        float pv[VPL];
#pragma unroll
        for (int v = 0; v < VPL; v++)
            pv[v] = p[(size_t)s * D + lane * VPL + v];
        float partial = 0.f;
#pragma unroll
        for (int v = 0; v < VPL; v++) {
            float tt = qv[v] + pv[v];
            tt = (tt > 0.f) ? tt : SLOPE * tt;   // leaky relu
            partial = fmaf(tt, av[v], partial);
        }
#pragma unroll
        for (int off = 32; off > 0; off >>= 1)
            partial += __shfl_xor(partial, off, 64);
        float es = expf(partial);                // unstabilized exp, per reference
        denom += es;
#pragma unroll
        for (int v = 0; v < VPL; v++)
            acc[v] = fmaf(es, pv[v], acc[v]);
    }

    float inv = (denom != 0.f) ? 1.f / denom : 0.f;  // zero-degree -> agg = 0
#pragma unroll
    for (int v = 0; v < VPL; v++) {
        float h = acc[v] * inv;
        float bb = bvec[lane * VPL + v];
        float o = (EPI == 0) ? gelu_erf(h + bb) : (h + bb);
        out[(size_t)node * D + lane * VPL + v] = o;
    }
}

// ---------------- launch ------------------------------------------------------
extern "C" void kernel_launch(void* const* d_in, const int* in_sizes, int n_in,
                              void* d_out, int out_size, void* d_ws, size_t ws_size,
                              hipStream_t stream)
{
    const float* x     = (const float*)d_in[0];
    const float* W0    = (const float*)d_in[1];
    const float* b0    = (const float*)d_in[2];
    const float* Wq1   = (const float*)d_in[3];
    const float* bq1   = (const float*)d_in[4];
    const float* Wp1   = (const float*)d_in[5];
    const float* bp1   = (const float*)d_in[6];
    const float* a1    = (const float*)d_in[7];
    const float* bg2   = (const float*)d_in[8];
    const float* Wq2   = (const float*)d_in[9];
    const float* bq2   = (const float*)d_in[10];
    const float* Wp2   = (const float*)d_in[11];
    const float* bp2   = (const float*)d_in[12];
    const float* a2    = (const float*)d_in[13];
    const float* b_out = (const float*)d_in[14];
    const int*   src   = (const int*)d_in[15];
    const int*   dst   = (const int*)d_in[16];

    const int N = in_sizes[0] / 128;
    const int E = in_sizes[15];
    float* out = (float*)d_out;

    // workspace carve
    float* m_buf = (float*)d_ws;
    float* q_buf = m_buf + (size_t)N * 128;
    float* p_buf = q_buf + (size_t)N * 128;
    int* offs    = (int*)(p_buf + (size_t)N * 128);
    int* cursor  = offs + (N + 1);
    int* csr_src = cursor + N;
    int* bsum    = csr_src + E;

    const int NB = (N + 255) / 256;

    // CSR build (counts in cursor)
    hipMemsetAsync(cursor, 0, (size_t)N * sizeof(int), stream);
    hist_kernel<<<(E + 255) / 256, 256, 0, stream>>>(dst, cursor, E);
    scan1_kernel<<<NB, 256, 0, stream>>>(cursor, offs, bsum, N);
    scan2_kernel<<<1, 256, 0, stream>>>(bsum, NB);
    scan3_kernel<<<NB, 256, 0, stream>>>(offs, bsum, cursor, N, E);
    scatter_kernel<<<(E + 255) / 256, 256, 0, stream>>>(src, dst, cursor, csr_src, E);

    // layer 0: m1 = gelu(x@W0 + b0)
    gemm_k128<128, 1><<<(N + 15) / 16, 256, 0, stream>>>(x, W0, b0, m_buf, N);
    // layer 1 projections
    gemm_k128<128, 0><<<(N + 15) / 16, 256, 0, stream>>>(m_buf, Wq1, bq1, q_buf, N);
    gemm_k128<128, 0><<<(N + 15) / 16, 256, 0, stream>>>(m_buf, Wp1, bp1, p_buf, N);
    // layer 1 GAT + fused m2 = gelu(h1 + bg2)  (m1 dead -> write m_buf)
    gat_agg<128, 0><<<(N + 3) / 4, 256, 0, stream>>>(q_buf, p_buf, a1, bg2,
                                                     offs, csr_src, m_buf, N);
    // layer 2 projections (reuse q/p buffers, stride 64)
    gemm_k128<64, 0><<<(N + 31) / 32, 256, 0, stream>>>(m_buf, Wq2, bq2, q_buf, N);
    gemm_k128<64, 0><<<(N + 31) / 32, 256, 0, stream>>>(m_buf, Wp2, bp2, p_buf, N);
    // layer 2 GAT + fused + b_out -> d_out
    gat_agg<64, 1><<<(N + 3) / 4, 256, 0, stream>>>(q_buf, p_buf, a2, b_out,
                                                    offs, csr_src, out, N);
}

// Round 2
// 467.355 us; speedup vs baseline: 1.3491x; 1.3491x over previous
//
#include <hip/hip_runtime.h>
#include <hip/hip_bf16.h>
#include <math.h>

// GAT 2-layer fused pipeline for MI355X (gfx950).
// Dims per reference: D_IN=D_H=128, D_OUT=64, SLOPE=0.2. All math fp32.
//
// Round-2 changes vs round-1:
//  - gat_agg: DPP wave reduction (6 v_add_f32_dpp + v_readlane) instead of
//    6x __shfl_xor (ds_bpermute + lane math); __expf; lrelu = max(t, 0.2t);
//    edge loop unrolled x2 for ILP.  ~90 -> ~30 VALU instrs/edge.
//  - gemm: 8 rows x 4 cols per thread (64 rows/block), LDS reads are
//    half-wave broadcasts (conflict-free); 32 FMA per 1 global + 8 LDS.

#define SLOPE 0.2f

__device__ __forceinline__ float gelu_erf(float x) {
    return 0.5f * x * (1.0f + erff(x * 0.70710678118654752f));
}

// Full-wave (64-lane) f32 sum via DPP; returns total broadcast to all lanes.
// Sequence: row_shr 1,2,4,8 (within 16-lane rows), row_bcast15, row_bcast31;
// total lands in lane 63, extracted with v_readlane (SGPR broadcast).
__device__ __forceinline__ float wave_sum_bcast(float x) {
    x += __int_as_float(__builtin_amdgcn_update_dpp(0, __float_as_int(x), 0x111, 0xF, 0xF, true));
    x += __int_as_float(__builtin_amdgcn_update_dpp(0, __float_as_int(x), 0x112, 0xF, 0xF, true));
    x += __int_as_float(__builtin_amdgcn_update_dpp(0, __float_as_int(x), 0x114, 0xF, 0xF, true));
    x += __int_as_float(__builtin_amdgcn_update_dpp(0, __float_as_int(x), 0x118, 0xF, 0xF, true));
    x += __int_as_float(__builtin_amdgcn_update_dpp(0, __float_as_int(x), 0x142, 0xF, 0xF, true));
    x += __int_as_float(__builtin_amdgcn_update_dpp(0, __float_as_int(x), 0x143, 0xF, 0xF, true));
    return __int_as_float(__builtin_amdgcn_readlane(__float_as_int(x), 63));
}

// ---------------- GEMM: out[N,C] = act(A[N,128] @ W[128,C] + bias) ----------
// 256 threads, 64 rows/block, each thread RPT rows x 4 cols.
// C=128: CG=32, RPT=8.  C=64: CG=16, RPT=4.
template <int C, int RPT, int ACT>
__global__ __launch_bounds__(256) void gemm_k128(
    const float* __restrict__ A, const float* __restrict__ W,
    const float* __restrict__ bias, float* __restrict__ out, int N)
{
    constexpr int CG   = C / 4;
    constexpr int ROWS = (256 / CG) * RPT;   // 64 for both configs
    __shared__ float Alds[ROWS][132];        // pad: rows start on distinct banks

    const int row0 = blockIdx.x * ROWS;
    const int t = threadIdx.x;

    // stage A tile (coalesced float4)
    constexpr int LD4 = (ROWS * 32) / 256;
#pragma unroll
    for (int i = 0; i < LD4; i++) {
        int idx = t + i * 256;
        int r = idx >> 5;
        int kc = idx & 31;
        float4 v = make_float4(0.f, 0.f, 0.f, 0.f);
        int gr = row0 + r;
        if (gr < N) v = reinterpret_cast<const float4*>(A + (size_t)gr * 128)[kc];
        reinterpret_cast<float4*>(&Alds[r][0])[kc] = v;
    }
    __syncthreads();

    const int cg = t % CG;
    const int rg = t / CG;
    const int r0 = rg * RPT;

    float4 acc[RPT];
#pragma unroll
    for (int r = 0; r < RPT; r++) acc[r] = make_float4(0.f, 0.f, 0.f, 0.f);

    const float4* Wv = reinterpret_cast<const float4*>(W);

#pragma unroll 4
    for (int k = 0; k < 128; k++) {
        float4 w = Wv[k * CG + cg];
#pragma unroll
        for (int r = 0; r < RPT; r++) {
            float a = Alds[r0 + r][k];   // half-wave broadcast: conflict-free
            acc[r].x = fmaf(a, w.x, acc[r].x);
            acc[r].y = fmaf(a, w.y, acc[r].y);
            acc[r].z = fmaf(a, w.z, acc[r].z);
            acc[r].w = fmaf(a, w.w, acc[r].w);
        }
    }

    float4 b = reinterpret_cast<const float4*>(bias)[cg];
#pragma unroll
    for (int r = 0; r < RPT; r++) {
        float4 o = acc[r];
        o.x += b.x; o.y += b.y; o.z += b.z; o.w += b.w;
        if (ACT == 1) {
            o.x = gelu_erf(o.x); o.y = gelu_erf(o.y);
            o.z = gelu_erf(o.z); o.w = gelu_erf(o.w);
        }
        int gr = row0 + r0 + r;
        if (gr < N) reinterpret_cast<float4*>(out + (size_t)gr * C)[cg] = o;
    }
}

// ---------------- CSR build --------------------------------------------------
__global__ __launch_bounds__(256) void hist_kernel(const int* __restrict__ dst,
                                                   int* __restrict__ cnt, int E)
{
    int i = blockIdx.x * 256 + threadIdx.x;
    if (i < E) atomicAdd(&cnt[dst[i]], 1);
}

__global__ __launch_bounds__(256) void scan1_kernel(const int* __restrict__ cnt,
                                                    int* __restrict__ offs,
                                                    int* __restrict__ bsum, int N)
{
    __shared__ int lds[256];
    int t = threadIdx.x;
    int i = blockIdx.x * 256 + t;
    int v = (i < N) ? cnt[i] : 0;
    lds[t] = v;
    __syncthreads();
    int x = v;
    for (int off = 1; off < 256; off <<= 1) {
        int y = (t >= off) ? lds[t - off] : 0;
        __syncthreads();
        x += y;
        lds[t] = x;
        __syncthreads();
    }
    if (i < N) offs[i] = x - v;
    if (t == 255) bsum[blockIdx.x] = x;
}

__global__ __launch_bounds__(256) void scan2_kernel(int* __restrict__ bsum, int NB)
{
    __shared__ int lds[256];
    int t = threadIdx.x;
    int v = (t < NB) ? bsum[t] : 0;
    lds[t] = v;
    __syncthreads();
    int x = v;
    for (int off = 1; off < 256; off <<= 1) {
        int y = (t >= off) ? lds[t - off] : 0;
        __syncthreads();
        x += y;
        lds[t] = x;
        __syncthreads();
    }
    if (t < NB) bsum[t] = x - v;
}

__global__ __launch_bounds__(256) void scan3_kernel(int* __restrict__ offs,
                                                    const int* __restrict__ bsum,
                                                    int* __restrict__ cursor,
                                                    int N, int E)
{
    int i = blockIdx.x * 256 + threadIdx.x;
    if (i < N) {
        int o = offs[i] + bsum[blockIdx.x];
        offs[i] = o;
        cursor[i] = o;
    }
    if (i == 0) offs[N] = E;
}

__global__ __launch_bounds__(256) void scatter_kernel(const int* __restrict__ src,
                                                      const int* __restrict__ dst,
                                                      int* __restrict__ cursor,
                                                      int* __restrict__ csr_src, int E)
{
    int i = blockIdx.x * 256 + threadIdx.x;
    if (i < E) {
        int d = dst[i];
        int pos = atomicAdd(&cursor[d], 1);
        csr_src[pos] = src[i];
    }
}

// ---------------- fused GAT edge-softmax + aggregation -----------------------
// One wave per dst node. Lane holds D/64 dims. Single pass:
//   acc = sum es*p[src], denom = sum es; out = epi(acc/denom).
// EPI 0: gelu(h + bvec);  EPI 1: h + bvec.
template <int D, int EPI>
__global__ __launch_bounds__(256) void gat_agg(
    const float* __restrict__ q, const float* __restrict__ p,
    const float* __restrict__ a, const float* __restrict__ bvec,
    const int* __restrict__ offs, const int* __restrict__ csr_src,
    float* __restrict__ out, int N)
{
    constexpr int VPL = D / 64;  // 2 (D=128) or 1 (D=64)
    int node = (int)((blockIdx.x * 256 + threadIdx.x) >> 6);
    int lane = threadIdx.x & 63;
    if (node >= N) return;  // wave-uniform

    float qv[VPL], av[VPL], acc[VPL];
#pragma unroll
    for (int v = 0; v < VPL; v++) {
        qv[v] = q[(size_t)node * D + lane * VPL + v];
        av[v] = a[lane * VPL + v];
        acc[v] = 0.f;
    }
    float denom = 0.f;

    const int e0 = offs[node], e1 = offs[node + 1];
    int e = e0;
    for (; e + 2 <= e1; e += 2) {
        int s0 = csr_src[e];
        int s1 = csr_src[e + 1];
        float pv0[VPL], pv1[VPL];
        if (VPL == 2) {
            float2 t0 = *reinterpret_cast<const float2*>(p + (size_t)s0 * D + lane * 2);
            float2 t1 = *reinterpret_cast<const float2*>(p + (size_t)s1 * D + lane * 2);
            pv0[0] = t0.x; pv0[1] = t0.y;
            pv1[0] = t1.x; pv1[1] = t1.y;
        } else {
            pv0[0] = p[(size_t)s0 * D + lane];
            pv1[0] = p[(size_t)s1 * D + lane];
        }
        float pa0 = 0.f, pa1 = 0.f;
#pragma unroll
        for (int v = 0; v < VPL; v++) {
            float t0 = qv[v] + pv0[v];
            float t1 = qv[v] + pv1[v];
            t0 = fmaxf(t0, SLOPE * t0);   // leaky relu (slope<1)
            t1 = fmaxf(t1, SLOPE * t1);
            pa0 = fmaf(t0, av[v], pa0);
            pa1 = fmaf(t1, av[v], pa1);
        }
        float s_tot0 = wave_sum_bcast(pa0);  // two independent DPP chains
        float s_tot1 = wave_sum_bcast(pa1);
        float es0 = __expf(s_tot0);
        float es1 = __expf(s_tot1);
        denom += es0 + es1;
#pragma unroll
        for (int v = 0; v < VPL; v++) {
            acc[v] = fmaf(es0, pv0[v], acc[v]);
            acc[v] = fmaf(es1, pv1[v], acc[v]);
        }
    }
    if (e < e1) {
        int s0 = csr_src[e];
        float pv0[VPL];
        if (VPL == 2) {
            float2 t0 = *reinterpret_cast<const float2*>(p + (size_t)s0 * D + lane * 2);
            pv0[0] = t0.x; pv0[1] = t0.y;
        } else {
            pv0[0] = p[(size_t)s0 * D + lane];
        }
        float pa0 = 0.f;
#pragma unroll
        for (int v = 0; v < VPL; v++) {
            float t0 = qv[v] + pv0[v];
            t0 = fmaxf(t0, SLOPE * t0);
            pa0 = fmaf(t0, av[v], pa0);
        }
        float es0 = __expf(wave_sum_bcast(pa0));
        denom += es0;
#pragma unroll
        for (int v = 0; v < VPL; v++)
            acc[v] = fmaf(es0, pv0[v], acc[v]);
    }

    float inv = (denom != 0.f) ? 1.f / denom : 0.f;  // zero-degree -> agg = 0
#pragma unroll
    for (int v = 0; v < VPL; v++) {
        float h = acc[v] * inv + bvec[lane * VPL + v];
        acc[v] = (EPI == 0) ? gelu_erf(h) : h;
    }
    if (VPL == 2) {
        float2 o; o.x = acc[0]; o.y = acc[1];
        *reinterpret_cast<float2*>(out + (size_t)node * D + lane * 2) = o;
    } else {
        out[(size_t)node * D + lane] = acc[0];
    }
}

// ---------------- launch ------------------------------------------------------
extern "C" void kernel_launch(void* const* d_in, const int* in_sizes, int n_in,
                              void* d_out, int out_size, void* d_ws, size_t ws_size,
                              hipStream_t stream)
{
    const float* x     = (const float*)d_in[0];
    const float* W0    = (const float*)d_in[1];
    const float* b0    = (const float*)d_in[2];
    const float* Wq1   = (const float*)d_in[3];
    const float* bq1   = (const float*)d_in[4];
    const float* Wp1   = (const float*)d_in[5];
    const float* bp1   = (const float*)d_in[6];
    const float* a1    = (const float*)d_in[7];
    const float* bg2   = (const float*)d_in[8];
    const float* Wq2   = (const float*)d_in[9];
    const float* bq2   = (const float*)d_in[10];
    const float* Wp2   = (const float*)d_in[11];
    const float* bp2   = (const float*)d_in[12];
    const float* a2    = (const float*)d_in[13];
    const float* b_out = (const float*)d_in[14];
    const int*   src   = (const int*)d_in[15];
    const int*   dst   = (const int*)d_in[16];

    const int N = in_sizes[0] / 128;
    const int E = in_sizes[15];
    float* out = (float*)d_out;

    // workspace carve
    float* m_buf = (float*)d_ws;
    float* q_buf = m_buf + (size_t)N * 128;
    float* p_buf = q_buf + (size_t)N * 128;
    int* offs    = (int*)(p_buf + (size_t)N * 128);
    int* cursor  = offs + (N + 1);
    int* csr_src = cursor + N;
    int* bsum    = csr_src + E;

    const int NB = (N + 255) / 256;   // <= 256 assumed (N <= 65536)

    // CSR build (counts in cursor)
    hipMemsetAsync(cursor, 0, (size_t)N * sizeof(int), stream);
    hist_kernel<<<(E + 255) / 256, 256, 0, stream>>>(dst, cursor, E);
    scan1_kernel<<<NB, 256, 0, stream>>>(cursor, offs, bsum, N);
    scan2_kernel<<<1, 256, 0, stream>>>(bsum, NB);
    scan3_kernel<<<NB, 256, 0, stream>>>(offs, bsum, cursor, N, E);
    scatter_kernel<<<(E + 255) / 256, 256, 0, stream>>>(src, dst, cursor, csr_src, E);

    // layer 0: m1 = gelu(x@W0 + b0)
    gemm_k128<128, 8, 1><<<(N + 63) / 64, 256, 0, stream>>>(x, W0, b0, m_buf, N);
    // layer 1 projections
    gemm_k128<128, 8, 0><<<(N + 63) / 64, 256, 0, stream>>>(m_buf, Wq1, bq1, q_buf, N);
    gemm_k128<128, 8, 0><<<(N + 63) / 64, 256, 0, stream>>>(m_buf, Wp1, bp1, p_buf, N);
    // layer 1 GAT + fused m2 = gelu(h1 + bg2)
    gat_agg<128, 0><<<(N + 3) / 4, 256, 0, stream>>>(q_buf, p_buf, a1, bg2,
                                                     offs, csr_src, m_buf, N);
    // layer 2 projections
    gemm_k128<64, 4, 0><<<(N + 63) / 64, 256, 0, stream>>>(m_buf, Wq2, bq2, q_buf, N);
    gemm_k128<64, 4, 0><<<(N + 63) / 64, 256, 0, stream>>>(m_buf, Wp2, bp2, p_buf, N);
    // layer 2 GAT + fused + b_out -> d_out
    gat_agg<64, 1><<<(N + 3) / 4, 256, 0, stream>>>(q_buf, p_buf, a2, b_out,
                                                    offs, csr_src, out, N);
}

// Round 3
// 449.275 us; speedup vs baseline: 1.4034x; 1.0402x over previous
//
#include <hip/hip_runtime.h>
#include <hip/hip_bf16.h>
#include <math.h>

// GAT 2-layer fused pipeline for MI355X (gfx950).
// Dims per reference: D_IN=D_H=128, D_OUT=64, SLOPE=0.2. All math fp32.
//
// Round-3 changes:
//  - gat_agg: wave-uniform node via readfirstlane -> scalar CSR walk
//    (s_load offs/csr_src, scalar loop, SGPR p-row bases), edge loop
//    unrolled x4 (4 gathers + 4 independent DPP chains in flight).
//  - gemm: dual-output (q and p share one A staging), 4 rows x 8 cols
//    per thread (C=128), K unrolled x4 with ds_read_b128 A fragments.

#define SLOPE 0.2f

__device__ __forceinline__ float gelu_erf(float x) {
    return 0.5f * x * (1.0f + erff(x * 0.70710678118654752f));
}

// Full-wave (64-lane) f32 sum via DPP; result broadcast via readlane 63.
__device__ __forceinline__ float wave_sum_bcast(float x) {
    x += __int_as_float(__builtin_amdgcn_update_dpp(0, __float_as_int(x), 0x111, 0xF, 0xF, true));
    x += __int_as_float(__builtin_amdgcn_update_dpp(0, __float_as_int(x), 0x112, 0xF, 0xF, true));
    x += __int_as_float(__builtin_amdgcn_update_dpp(0, __float_as_int(x), 0x114, 0xF, 0xF, true));
    x += __int_as_float(__builtin_amdgcn_update_dpp(0, __float_as_int(x), 0x118, 0xF, 0xF, true));
    x += __int_as_float(__builtin_amdgcn_update_dpp(0, __float_as_int(x), 0x142, 0xF, 0xF, true));
    x += __int_as_float(__builtin_amdgcn_update_dpp(0, __float_as_int(x), 0x143, 0xF, 0xF, true));
    return __int_as_float(__builtin_amdgcn_readlane(__float_as_int(x), 63));
}

// ---------------- GEMM: out[N,C] = act(A[N,128] @ W[128,C] + bias) ----------
// 256 threads, 64 rows/block. Thread: 4 rows x (COLS4*4) cols x (1 or 2 outs).
template <int C, int ACT, bool DUAL>
__global__ __launch_bounds__(256) void gemm_k128(
    const float* __restrict__ A,
    const float* __restrict__ W1, const float* __restrict__ b1,
    const float* __restrict__ W2, const float* __restrict__ b2,
    float* __restrict__ out1, float* __restrict__ out2, int N)
{
    constexpr int C4    = C / 4;
    constexpr int COLS4 = (C == 128) ? 2 : 1;   // float4-cols per thread/out
    constexpr int CG    = C4 / COLS4;           // 16
    constexpr int RPT   = 4;
    constexpr int ROWS  = (256 / CG) * RPT;     // 64
    __shared__ __align__(16) float Alds[ROWS][132];

    const int row0 = blockIdx.x * ROWS;
    const int t = threadIdx.x;

    constexpr int LD4 = (ROWS * 32) / 256;      // 8
#pragma unroll
    for (int i = 0; i < LD4; i++) {
        int idx = t + i * 256;
        int r = idx >> 5, kc = idx & 31;
        float4 v = make_float4(0.f, 0.f, 0.f, 0.f);
        int gr = row0 + r;
        if (gr < N) v = reinterpret_cast<const float4*>(A + (size_t)gr * 128)[kc];
        reinterpret_cast<float4*>(&Alds[r][0])[kc] = v;
    }
    __syncthreads();

    const int cg = t % CG;
    const int r0 = (t / CG) * RPT;

    float4 acc1[COLS4][RPT];
    float4 acc2[COLS4][RPT];
#pragma unroll
    for (int c = 0; c < COLS4; c++)
#pragma unroll
        for (int r = 0; r < RPT; r++) {
            acc1[c][r] = make_float4(0.f, 0.f, 0.f, 0.f);
            acc2[c][r] = make_float4(0.f, 0.f, 0.f, 0.f);
        }

    const float4* W1v = reinterpret_cast<const float4*>(W1);
    const float4* W2v = reinterpret_cast<const float4*>(W2);

#pragma unroll 2
    for (int k4 = 0; k4 < 32; k4++) {
        float4 af[RPT];
#pragma unroll
        for (int r = 0; r < RPT; r++)
            af[r] = *reinterpret_cast<const float4*>(&Alds[r0 + r][k4 * 4]);
#pragma unroll
        for (int kk = 0; kk < 4; kk++) {
            int k = k4 * 4 + kk;
            float as[RPT];
#pragma unroll
            for (int r = 0; r < RPT; r++) {
                const float* fp = reinterpret_cast<const float*>(&af[r]);
                as[r] = fp[kk];
            }
#pragma unroll
            for (int c = 0; c < COLS4; c++) {
                float4 w1 = W1v[k * C4 + cg * COLS4 + c];
#pragma unroll
                for (int r = 0; r < RPT; r++) {
                    acc1[c][r].x = fmaf(as[r], w1.x, acc1[c][r].x);
                    acc1[c][r].y = fmaf(as[r], w1.y, acc1[c][r].y);
                    acc1[c][r].z = fmaf(as[r], w1.z, acc1[c][r].z);
                    acc1[c][r].w = fmaf(as[r], w1.w, acc1[c][r].w);
                }
                if (DUAL) {
                    float4 w2 = W2v[k * C4 + cg * COLS4 + c];
#pragma unroll
                    for (int r = 0; r < RPT; r++) {
                        acc2[c][r].x = fmaf(as[r], w2.x, acc2[c][r].x);
                        acc2[c][r].y = fmaf(as[r], w2.y, acc2[c][r].y);
                        acc2[c][r].z = fmaf(as[r], w2.z, acc2[c][r].z);
                        acc2[c][r].w = fmaf(as[r], w2.w, acc2[c][r].w);
                    }
                }
            }
        }
    }

#pragma unroll
    for (int c = 0; c < COLS4; c++) {
        float4 bb1 = reinterpret_cast<const float4*>(b1)[cg * COLS4 + c];
        float4 bb2 = DUAL ? reinterpret_cast<const float4*>(b2)[cg * COLS4 + c]
                          : make_float4(0.f, 0.f, 0.f, 0.f);
#pragma unroll
        for (int r = 0; r < RPT; r++) {
            int gr = row0 + r0 + r;
            if (gr >= N) continue;
            float4 o = acc1[c][r];
            o.x += bb1.x; o.y += bb1.y; o.z += bb1.z; o.w += bb1.w;
            if (ACT == 1) {
                o.x = gelu_erf(o.x); o.y = gelu_erf(o.y);
                o.z = gelu_erf(o.z); o.w = gelu_erf(o.w);
            }
            reinterpret_cast<float4*>(out1 + (size_t)gr * C)[cg * COLS4 + c] = o;
            if (DUAL) {
                float4 o2 = acc2[c][r];
                o2.x += bb2.x; o2.y += bb2.y; o2.z += bb2.z; o2.w += bb2.w;
                reinterpret_cast<float4*>(out2 + (size_t)gr * C)[cg * COLS4 + c] = o2;
            }
        }
    }
}

// ---------------- CSR build --------------------------------------------------
__global__ __launch_bounds__(256) void hist_kernel(const int* __restrict__ dst,
                                                   int* __restrict__ cnt, int E)
{
    int i = blockIdx.x * 256 + threadIdx.x;
    if (i < E) atomicAdd(&cnt[dst[i]], 1);
}

__global__ __launch_bounds__(256) void scan1_kernel(const int* __restrict__ cnt,
                                                    int* __restrict__ offs,
                                                    int* __restrict__ bsum, int N)
{
    __shared__ int lds[256];
    int t = threadIdx.x;
    int i = blockIdx.x * 256 + t;
    int v = (i < N) ? cnt[i] : 0;
    lds[t] = v;
    __syncthreads();
    int x = v;
    for (int off = 1; off < 256; off <<= 1) {
        int y = (t >= off) ? lds[t - off] : 0;
        __syncthreads();
        x += y;
        lds[t] = x;
        __syncthreads();
    }
    if (i < N) offs[i] = x - v;
    if (t == 255) bsum[blockIdx.x] = x;
}

__global__ __launch_bounds__(256) void scan2_kernel(int* __restrict__ bsum, int NB)
{
    __shared__ int lds[256];
    int t = threadIdx.x;
    int v = (t < NB) ? bsum[t] : 0;
    lds[t] = v;
    __syncthreads();
    int x = v;
    for (int off = 1; off < 256; off <<= 1) {
        int y = (t >= off) ? lds[t - off] : 0;
        __syncthreads();
        x += y;
        lds[t] = x;
        __syncthreads();
    }
    if (t < NB) bsum[t] = x - v;
}

__global__ __launch_bounds__(256) void scan3_kernel(int* __restrict__ offs,
                                                    const int* __restrict__ bsum,
                                                    int* __restrict__ cursor,
                                                    int N, int E)
{
    int i = blockIdx.x * 256 + threadIdx.x;
    if (i < N) {
        int o = offs[i] + bsum[blockIdx.x];
        offs[i] = o;
        cursor[i] = o;
    }
    if (i == 0) offs[N] = E;
}

__global__ __launch_bounds__(256) void scatter_kernel(const int* __restrict__ src,
                                                      const int* __restrict__ dst,
                                                      int* __restrict__ cursor,
                                                      int* __restrict__ csr_src, int E)
{
    int i = blockIdx.x * 256 + threadIdx.x;
    if (i < E) {
        int d = dst[i];
        int pos = atomicAdd(&cursor[d], 1);
        csr_src[pos] = src[i];
    }
}

// ---------------- fused GAT edge-softmax + aggregation -----------------------
// One wave per dst node (wave-uniform via readfirstlane -> scalar CSR walk).
// Single pass: acc = sum es*p[src], denom = sum es; out = epi(acc/denom).
template <int D, int EPI>
__global__ __launch_bounds__(256) void gat_agg(
    const float* __restrict__ q, const float* __restrict__ p,
    const float* __restrict__ a, const float* __restrict__ bvec,
    const int* __restrict__ offs, const int* __restrict__ csr_src,
    float* __restrict__ out, int N)
{
    constexpr int VPL = D / 64;  // 2 (D=128) or 1 (D=64)
    const int lane = threadIdx.x & 63;
    const int node = __builtin_amdgcn_readfirstlane(blockIdx.x * 4 + (threadIdx.x >> 6));
    if (node >= N) return;  // scalar branch

    float qv[VPL], av[VPL], acc[VPL];
#pragma unroll
    for (int v = 0; v < VPL; v++) {
        qv[v] = q[(size_t)node * D + lane * VPL + v];
        av[v] = a[lane * VPL + v];
        acc[v] = 0.f;
    }
    float denom = 0.f;

    const int e0 = offs[node], e1 = offs[node + 1];   // s_load
    int e = e0;

    for (; e + 4 <= e1; e += 4) {
        int s0 = csr_src[e + 0];
        int s1 = csr_src[e + 1];
        int s2 = csr_src[e + 2];
        int s3 = csr_src[e + 3];
        float pv0[VPL], pv1[VPL], pv2[VPL], pv3[VPL];
        if (VPL == 2) {
            float2 t0 = *reinterpret_cast<const float2*>(p + (size_t)s0 * D + lane * 2);
            float2 t1 = *reinterpret_cast<const float2*>(p + (size_t)s1 * D + lane * 2);
            float2 t2 = *reinterpret_cast<const float2*>(p + (size_t)s2 * D + lane * 2);
            float2 t3 = *reinterpret_cast<const float2*>(p + (size_t)s3 * D + lane * 2);
            pv0[0] = t0.x; pv0[1] = t0.y;
            pv1[0] = t1.x; pv1[1] = t1.y;
            pv2[0] = t2.x; pv2[1] = t2.y;
            pv3[0] = t3.x; pv3[1] = t3.y;
        } else {
            pv0[0] = p[(size_t)s0 * D + lane];
            pv1[0] = p[(size_t)s1 * D + lane];
            pv2[0] = p[(size_t)s2 * D + lane];
            pv3[0] = p[(size_t)s3 * D + lane];
        }
        float pa0 = 0.f, pa1 = 0.f, pa2 = 0.f, pa3 = 0.f;
#pragma unroll
        for (int v = 0; v < VPL; v++) {
            float t0 = qv[v] + pv0[v];
            float t1 = qv[v] + pv1[v];
            float t2 = qv[v] + pv2[v];
            float t3 = qv[v] + pv3[v];
            t0 = fmaxf(t0, SLOPE * t0);
            t1 = fmaxf(t1, SLOPE * t1);
            t2 = fmaxf(t2, SLOPE * t2);
            t3 = fmaxf(t3, SLOPE * t3);
            pa0 = fmaf(t0, av[v], pa0);
            pa1 = fmaf(t1, av[v], pa1);
            pa2 = fmaf(t2, av[v], pa2);
            pa3 = fmaf(t3, av[v], pa3);
        }
        // 4 independent DPP chains — compiler interleaves them
        float w0 = wave_sum_bcast(pa0);
        float w1 = wave_sum_bcast(pa1);
        float w2 = wave_sum_bcast(pa2);
        float w3 = wave_sum_bcast(pa3);
        float es0 = __expf(w0);
        float es1 = __expf(w1);
        float es2 = __expf(w2);
        float es3 = __expf(w3);
        denom += (es0 + es1) + (es2 + es3);
#pragma unroll
        for (int v = 0; v < VPL; v++) {
            acc[v] = fmaf(es0, pv0[v], acc[v]);
            acc[v] = fmaf(es1, pv1[v], acc[v]);
            acc[v] = fmaf(es2, pv2[v], acc[v]);
            acc[v] = fmaf(es3, pv3[v], acc[v]);
        }
    }
    for (; e < e1; e++) {
        int s0 = csr_src[e];
        float pv0[VPL];
        if (VPL == 2) {
            float2 t0 = *reinterpret_cast<const float2*>(p + (size_t)s0 * D + lane * 2);
            pv0[0] = t0.x; pv0[1] = t0.y;
        } else {
            pv0[0] = p[(size_t)s0 * D + lane];
        }
        float pa0 = 0.f;
#pragma unroll
        for (int v = 0; v < VPL; v++) {
            float t0 = qv[v] + pv0[v];
            t0 = fmaxf(t0, SLOPE * t0);
            pa0 = fmaf(t0, av[v], pa0);
        }
        float es0 = __expf(wave_sum_bcast(pa0));
        denom += es0;
#pragma unroll
        for (int v = 0; v < VPL; v++)
            acc[v] = fmaf(es0, pv0[v], acc[v]);
    }

    float inv = (denom != 0.f) ? 1.f / denom : 0.f;  // zero-degree -> agg = 0
#pragma unroll
    for (int v = 0; v < VPL; v++) {
        float h = acc[v] * inv + bvec[lane * VPL + v];
        acc[v] = (EPI == 0) ? gelu_erf(h) : h;
    }
    if (VPL == 2) {
        float2 o; o.x = acc[0]; o.y = acc[1];
        *reinterpret_cast<float2*>(out + (size_t)node * D + lane * 2) = o;
    } else {
        out[(size_t)node * D + lane] = acc[0];
    }
}

// ---------------- launch ------------------------------------------------------
extern "C" void kernel_launch(void* const* d_in, const int* in_sizes, int n_in,
                              void* d_out, int out_size, void* d_ws, size_t ws_size,
                              hipStream_t stream)
{
    const float* x     = (const float*)d_in[0];
    const float* W0    = (const float*)d_in[1];
    const float* b0    = (const float*)d_in[2];
    const float* Wq1   = (const float*)d_in[3];
    const float* bq1   = (const float*)d_in[4];
    const float* Wp1   = (const float*)d_in[5];
    const float* bp1   = (const float*)d_in[6];
    const float* a1    = (const float*)d_in[7];
    const float* bg2   = (const float*)d_in[8];
    const float* Wq2   = (const float*)d_in[9];
    const float* bq2   = (const float*)d_in[10];
    const float* Wp2   = (const float*)d_in[11];
    const float* bp2   = (const float*)d_in[12];
    const float* a2    = (const float*)d_in[13];
    const float* b_out = (const float*)d_in[14];
    const int*   src   = (const int*)d_in[15];
    const int*   dst   = (const int*)d_in[16];

    const int N = in_sizes[0] / 128;
    const int E = in_sizes[15];
    float* out = (float*)d_out;

    // workspace carve
    float* m_buf = (float*)d_ws;
    float* q_buf = m_buf + (size_t)N * 128;
    float* p_buf = q_buf + (size_t)N * 128;
    int* offs    = (int*)(p_buf + (size_t)N * 128);
    int* cursor  = offs + (N + 1);
    int* csr_src = cursor + N;
    int* bsum    = csr_src + E;

    const int NB = (N + 255) / 256;   // <= 256 assumed

    // CSR build (counts in cursor)
    hipMemsetAsync(cursor, 0, (size_t)N * sizeof(int), stream);
    hist_kernel<<<(E + 255) / 256, 256, 0, stream>>>(dst, cursor, E);
    scan1_kernel<<<NB, 256, 0, stream>>>(cursor, offs, bsum, N);
    scan2_kernel<<<1, 256, 0, stream>>>(bsum, NB);
    scan3_kernel<<<NB, 256, 0, stream>>>(offs, bsum, cursor, N, E);
    scatter_kernel<<<(E + 255) / 256, 256, 0, stream>>>(src, dst, cursor, csr_src, E);

    const int GB = (N + 63) / 64;

    // layer 0: m1 = gelu(x@W0 + b0)
    gemm_k128<128, 1, false><<<GB, 256, 0, stream>>>(x, W0, b0, nullptr, nullptr,
                                                     m_buf, nullptr, N);
    // layer 1 projections (dual)
    gemm_k128<128, 0, true><<<GB, 256, 0, stream>>>(m_buf, Wq1, bq1, Wp1, bp1,
                                                    q_buf, p_buf, N);
    // layer 1 GAT + fused m2 = gelu(h1 + bg2)
    gat_agg<128, 0><<<(N + 3) / 4, 256, 0, stream>>>(q_buf, p_buf, a1, bg2,
                                                     offs, csr_src, m_buf, N);
    // layer 2 projections (dual)
    gemm_k128<64, 0, true><<<GB, 256, 0, stream>>>(m_buf, Wq2, bq2, Wp2, bp2,
                                                   q_buf, p_buf, N);
    // layer 2 GAT + fused + b_out -> d_out
    gat_agg<64, 1><<<(N + 3) / 4, 256, 0, stream>>>(q_buf, p_buf, a2, b_out,
                                                    offs, csr_src, out, N);
}